// Round 13
// baseline (170.189 us; speedup 1.0000x reference)
//
#include <hip/hip_runtime.h>

#pragma clang fp contract(off)

typedef unsigned int u32;
typedef unsigned long long u64;
typedef long long i64;

#define N_ROWS 32768
#define NCLS 81
#define TOPK 4096
#define MAXCAND 327680
#define EQCAP 8192
#define IMGW_M1 1332.0f
#define IMGH_M1 799.0f

// k_cand geometry: 8 threads/row, 32 rows/block, 1024 blocks
#define CAND_THREADS 256
#define RPB 32
#define CAND_GRID (N_ROWS / RPB)          // 1024
#define CPT 11
#define BLK_CAND_CAP 640                  // 32 rows * <=19 cand/row = 608 max
#define ROW_F4 ((RPB * NCLS) / 4)         // 648 float4 per block slice (exactly)

// level-1 bins: f32 bits of p in (0.05, 1.0] -> hi16 in [0x3D4C, 0x3F80]
#define H1_BASE 0x3D4Cu
#define H1_BINS 576
#define H1_SLICES 64

#define COLL_GRID 512

// k_nms LDS staging cap
#define MCAP 2048

// fast f64 exp for d <= 0 (clamped at -45). Cody-Waite + Taylor-13.
// Relative error ~3e-16 — decisions have >= f32-ulp (6e-8) margins.
__device__ inline double fast_exp_neg(double d) {
    if (d < -45.0) return 0.0;
    const double L2E    = 1.4426950408889634074;
    const double LN2_HI = 6.93147180369123816490e-01;
    const double LN2_LO = 1.90821492927058770002e-10;
    double n = __builtin_rint(d * L2E);
    double r = __builtin_fma(-n, LN2_HI, d);
    r = __builtin_fma(-n, LN2_LO, r);
    double p = 1.0 / 6227020800.0;
    p = __builtin_fma(p, r, 1.0 / 479001600.0);
    p = __builtin_fma(p, r, 1.0 / 39916800.0);
    p = __builtin_fma(p, r, 1.0 / 3628800.0);
    p = __builtin_fma(p, r, 1.0 / 362880.0);
    p = __builtin_fma(p, r, 1.0 / 40320.0);
    p = __builtin_fma(p, r, 1.0 / 5040.0);
    p = __builtin_fma(p, r, 1.0 / 720.0);
    p = __builtin_fma(p, r, 1.0 / 120.0);
    p = __builtin_fma(p, r, 1.0 / 24.0);
    p = __builtin_fma(p, r, 1.0 / 6.0);
    p = __builtin_fma(p, r, 0.5);
    p = __builtin_fma(p, r, 1.0);
    p = __builtin_fma(p, r, 1.0);
    i64 ni = (i64)n;
    double sc = __longlong_as_double((i64)(1023 + ni) << 52);
    return p * sc;
}

// softmax + threshold + DENSE compaction + FUSED level-1 histogram.
// e[i] computed INDEPENDENTLY (ILP, no serial s-chain), summed in the same
// sequential order as the passing R12 kernel -> bit-identical s; e reused in
// pass 2 (halves exp count). Decisions bit-identical.
__global__ void __launch_bounds__(256) k_cand(const float* __restrict__ x,
                                              u32* __restrict__ candKey,
                                              u32* __restrict__ candIdx,
                                              u32* __restrict__ cnt,
                                              u32* __restrict__ hist1p) {
    __shared__ float4 lx4[ROW_F4];
    __shared__ u32 lK[BLK_CAND_CAP];
    __shared__ u32 lI[BLK_CAND_CAP];
    __shared__ u32 lh[H1_BINS];
    __shared__ u32 lcnt;
    __shared__ u32 gbaseSh;
    float* lx = (float*)lx4;
    const int t = threadIdx.x;
    if (t == 0) lcnt = 0;
    for (int i = t; i < H1_BINS; i += CAND_THREADS) lh[i] = 0;

    const float4* xv = (const float4*)x + (size_t)blockIdx.x * ROW_F4;
    for (int i = t; i < ROW_F4; i += CAND_THREADS) lx4[i] = xv[i];
    __syncthreads();

    const int rl = t >> 3;
    const int q = t & 7;
    const int c0 = q * 10;
    const int cEff = (q == 7) ? 11 : 10;
    const int row = blockIdx.x * RPB + rl;
    const float* xr = lx + rl * NCLS;

    float v[CPT];
    #pragma unroll
    for (int i = 0; i < CPT; i++) v[i] = (i < cEff) ? xr[c0 + i] : -1.0e30f;

    float m = v[0];
    #pragma unroll
    for (int i = 1; i < CPT; i++) m = fmaxf(m, v[i]);
    m = fmaxf(m, __shfl_xor(m, 1));
    m = fmaxf(m, __shfl_xor(m, 2));
    m = fmaxf(m, __shfl_xor(m, 4));

    // independent exps (ILP) ...
    double e[CPT];
    #pragma unroll
    for (int i = 0; i < CPT; i++) {
        if (i < cEff) {
            float d = v[i] - m;                   // f32 subtract, as reference
            e[i] = fast_exp_neg((double)d);
        } else e[i] = 0.0;
    }
    // ... summed in the SAME sequential order as before -> bit-identical s
    double s = 0.0;
    #pragma unroll
    for (int i = 0; i < CPT; i++) if (i < cEff) s += e[i];
    s += __shfl_xor(s, 1);
    s += __shfl_xor(s, 2);
    s += __shfl_xor(s, 4);

    // float(p)>0.05f  <=>  p > 0.05f + 2^-29 (half-ulp midpoint); f64 mul, no div
    const double THRMID = (double)0.05f + 0x1.0p-29;
    double ethr = THRMID * s;
    #pragma unroll
    for (int i = 0; i < CPT; i++) {
        int c = c0 + i;
        if (i < cEff && c != 0 && e[i] > ethr) {
            float pf = (float)(e[i] / s);         // exact f64 division, rare
            u32 slot = atomicAdd(&lcnt, 1u);
            lK[slot] = __float_as_uint(pf);
            lI[slot] = (u32)(row * NCLS + c);
        }
    }
    __syncthreads();
    u32 tot = lcnt;
    if (t == 0) gbaseSh = tot ? atomicAdd(&cnt[0], tot) : 0u;
    // LDS histogram of this block's keys
    for (u32 i = t; i < tot; i += CAND_THREADS) {
        u32 b = (lK[i] >> 16) - H1_BASE;
        if (b < (u32)H1_BINS) atomicAdd(&lh[b], 1u);
    }
    __syncthreads();
    u32 gbase = gbaseSh;
    for (u32 i = t; i < tot; i += CAND_THREADS) {
        u32 g = gbase + i;
        if (g < MAXCAND) {
            candKey[g] = lK[i];
            candIdx[g] = lI[i];
        }
    }
    // merge nonzero bins into slice (blockIdx & 63): depth <= 16 per address
    u32 ob = (blockIdx.x & (H1_SLICES - 1)) * H1_BINS;
    for (int i = t; i < H1_BINS; i += CAND_THREADS) {
        u32 h = lh[i];
        if (h) atomicAdd(&hist1p[ob + i], h);
    }
}

// fused cutoff finder, all-LDS, dense pipelined scans.
// Publishes: cnt[5]=cutKey, cnt[6]=need, cnt[1]=nsel, cnt[3]=B, sufG[0..576]
__global__ void __launch_bounds__(1024) k_mid(const u32* __restrict__ candKey,
                                              const u32* __restrict__ hist1p,
                                              u32* __restrict__ cnt,
                                              u32* __restrict__ sufG) {
    __shared__ u32 cs[1024];
    __shared__ u32 h2[4096];
    __shared__ u32 h3[16];
    __shared__ u32 sB, sAcc, sB2, sAcc2, sFound;
    int t = threadIdx.x;
    if (t == 0) sFound = 0;
    u32 s1 = 0;
    if (t < H1_BINS) {
        for (int j = 0; j < H1_SLICES; j++) s1 += hist1p[j * H1_BINS + t];
    }
    cs[t] = (t < H1_BINS) ? s1 : 0u;
    for (int i = t; i < 4096; i += 1024) h2[i] = 0;
    if (t < 16) h3[t] = 0;
    __syncthreads();
    for (int d = 1; d < 1024; d <<= 1) {          // inclusive suffix sum
        u32 v = (t + d < 1024) ? cs[t + d] : 0u;
        __syncthreads();
        cs[t] += v;
        __syncthreads();
    }
    if (t < 577) sufG[t] = cs[t];                 // cs[576] == 0 naturally
    {
        u32 S_t = cs[t];
        u32 S_next = (t < 1023) ? cs[t + 1] : 0u;
        if (S_next < TOPK && S_t >= TOPK) { sB = (u32)t; sAcc = S_next; sFound = 1; }
    }
    __syncthreads();
    if (!sFound) {                                // degenerate: < TOPK candidates
        if (t < 577) sufG[t] = 0u;
        if (t == 0) { cnt[5] = 0xFFFFFFFFu; cnt[6] = 0u; cnt[1] = 0u; cnt[3] = 0u; }
        return;
    }
    const u32 Bhi = sB + H1_BASE;
    const u32 n = cnt[0] < (u32)MAXCAND ? cnt[0] : (u32)MAXCAND;
    for (u32 i = t; i < n; i += 1024) {
        u32 k = candKey[i];
        if ((k >> 16) == Bhi) atomicAdd(&h2[(k >> 4) & 0xFFFu], 1u);
    }
    __syncthreads();
    u32 c4 = h2[4 * t] + h2[4 * t + 1] + h2[4 * t + 2] + h2[4 * t + 3];
    __syncthreads();
    cs[t] = c4;
    __syncthreads();
    for (int d = 1; d < 1024; d <<= 1) {
        u32 v = (t + d < 1024) ? cs[t + d] : 0u;
        __syncthreads();
        cs[t] += v;
        __syncthreads();
    }
    {
        u32 C = sAcc;
        u32 S_t = C + cs[t];
        u32 S_next = C + ((t < 1023) ? cs[t + 1] : 0u);
        if (S_next < TOPK && S_t >= TOPK) {
            u32 acc = S_next;
            int b2 = 4 * t;
            for (int b = 4 * t + 3; b >= 4 * t; b--) {
                u32 h = h2[b];
                if (acc + h >= TOPK) { b2 = b; break; }
                acc += h;
            }
            sB2 = (u32)b2; sAcc2 = acc;
        }
    }
    __syncthreads();
    const u32 pre28 = (Bhi << 12) | sB2;
    for (u32 i = t; i < n; i += 1024) {
        u32 k = candKey[i];
        if ((k >> 4) == pre28) atomicAdd(&h3[k & 0xFu], 1u);
    }
    __syncthreads();
    if (t == 0) {
        u32 acc = sAcc2;
        int L = 0;
        for (int b = 15; b >= 0; b--) {
            u32 h = h3[b];
            if (acc + h >= TOPK) { L = b; break; }
            acc += h;
        }
        cnt[5] = (pre28 << 4) | (u32)L;           // exact cutoff key
        cnt[6] = TOPK - acc;                      // take from ==cutoff set
        cnt[1] = acc;                             // nsel (# keys > cut)
        cnt[3] = sB;                              // cutoff bin index
    }
}

// scatter selected candidates directly into per-bin segments of sel[]
__global__ void __launch_bounds__(256) k_collect(const u32* __restrict__ candKey,
                                                 const u32* __restrict__ candIdx,
                                                 u32* __restrict__ cnt,
                                                 const u32* __restrict__ sufG,
                                                 u32* __restrict__ binCur,
                                                 u64* __restrict__ sel,
                                                 u32* __restrict__ eqI) {
    u32 n = cnt[0] < (u32)MAXCAND ? cnt[0] : (u32)MAXCAND;
    u32 cut = cnt[5];
    u32 stride = COLL_GRID * 256;
    for (u32 i = blockIdx.x * 256 + threadIdx.x; i < n; i += stride) {
        u32 k = candKey[i];
        if (k > cut) {
            u32 b = (k >> 16) - H1_BASE;          // b >= B guaranteed (k > cut)
            u32 pos = sufG[b + 1] + atomicAdd(&binCur[b], 1u);
            if (pos < (u32)TOPK)
                sel[pos] = ((u64)k << 32) | (u64)(0xFFFFFFFFu - candIdx[i]);
        } else if (k == cut) {
            u32 e2 = atomicAdd(&cnt[2], 1u);
            if (e2 < (u32)EQCAP) eqI[e2] = candIdx[i];
        }
    }
}

// distributed ranking: one block per level-1 bin; within-bin quadratic rank
// over composite (value-desc, idx-asc). Block 576 handles ==cutoff + tail.
__global__ void __launch_bounds__(256) k_binrank(const u64* __restrict__ sel,
                                                 const u32* __restrict__ eqI,
                                                 const u32* __restrict__ cnt,
                                                 const u32* __restrict__ sufG,
                                                 const float* __restrict__ boxes,
                                                 float* __restrict__ rboxes,
                                                 float* __restrict__ rvals,
                                                 int* __restrict__ rlabel,
                                                 float* __restrict__ out) {
    const int t = threadIdx.x;
    const u32 nsel = cnt[1] < (u32)TOPK ? cnt[1] : (u32)TOPK;

    if (blockIdx.x == H1_BINS) {                  // eq + tail block
        u32 m = cnt[2] < (u32)EQCAP ? cnt[2] : (u32)EQCAP;
        u32 need = cnt[6];
        if (nsel + need > (u32)TOPK) need = TOPK - nsel;
        u32 cut = cnt[5];
        u32 covered = nsel + need;
        for (u32 r = covered + t; r < TOPK; r += 256) {   // degenerate-only
            rboxes[r * 4 + 0] = 0; rboxes[r * 4 + 1] = 0;
            rboxes[r * 4 + 2] = 0; rboxes[r * 4 + 3] = 0;
            rvals[r] = 0.0f; rlabel[r] = 0;
            out[TOPK * 5 + r] = 0.0f;
            out[TOPK * 6 + r] = 0.0f;
            float* d = out + (size_t)r * 5;
            d[0] = 0; d[1] = 0; d[2] = 0; d[3] = 0; d[4] = 0;
        }
        for (u32 j = t; j < m; j += 256) {
            u32 v = eqI[j];
            u32 rho = 0;
            for (u32 k = 0; k < m; k++) rho += (eqI[k] < v) ? 1u : 0u;  // unique
            if (rho < need) {
                u32 r = nsel + rho;
                float val = __uint_as_float(cut);
                u32 bi = v / NCLS;
                u32 lab = v % NCLS;
                const float* bp = boxes + (size_t)bi * 4;
                float x1 = fminf(fmaxf(bp[0], 0.0f), IMGW_M1);
                float y1 = fminf(fmaxf(bp[1], 0.0f), IMGH_M1);
                float x2 = fminf(fmaxf(bp[2], 0.0f), IMGW_M1);
                float y2 = fminf(fmaxf(bp[3], 0.0f), IMGH_M1);
                rboxes[r * 4 + 0] = x1; rboxes[r * 4 + 1] = y1;
                rboxes[r * 4 + 2] = x2; rboxes[r * 4 + 3] = y2;
                rvals[r] = val;
                rlabel[r] = (int)lab;
                out[TOPK * 5 + r] = (float)lab;
            }
        }
        return;
    }

    __shared__ u64 seg[TOPK];                     // 32 KB (worst segment = nsel)
    const u32 b = blockIdx.x;
    const u32 B = cnt[3];
    if (b < B) return;
    u32 start = sufG[b + 1];
    u32 end = (b == B) ? nsel : sufG[b];
    if (end > (u32)TOPK) end = TOPK;
    if (start >= end) return;
    u32 len = end - start;
    for (u32 i = t; i < len; i += 256) seg[i] = sel[start + i];
    __syncthreads();
    for (u32 i = t; i < len; i += 256) {
        u64 c = seg[i];
        u32 r = start;
        for (u32 j = 0; j < len; j++) r += (seg[j] > c) ? 1u : 0u;
        u32 idx = 0xFFFFFFFFu - (u32)(c & 0xFFFFFFFFull);
        float val = __uint_as_float((u32)(c >> 32));
        u32 bi = idx / NCLS;
        u32 lab = idx % NCLS;
        const float* bp = boxes + (size_t)bi * 4;
        float x1 = fminf(fmaxf(bp[0], 0.0f), IMGW_M1);
        float y1 = fminf(fmaxf(bp[1], 0.0f), IMGH_M1);
        float x2 = fminf(fmaxf(bp[2], 0.0f), IMGW_M1);
        float y2 = fminf(fmaxf(bp[3], 0.0f), IMGH_M1);
        rboxes[r * 4 + 0] = x1; rboxes[r * 4 + 1] = y1;
        rboxes[r * 4 + 2] = x2; rboxes[r * 4 + 3] = y2;
        rvals[r] = val;
        rlabel[r] = (int)lab;
        out[TOPK * 5 + r] = (float)lab;           // labels (unmasked in reference)
    }
}

// ---- tiled bitmask greedy NMS (R11/R12, verified) ----
__device__ inline float4 nms_box(u32 g, const float4* __restrict__ boxL,
                                 const float* __restrict__ rboxes,
                                 const unsigned short* __restrict__ memRank, float off) {
    if (g < (u32)MCAP) return boxL[g];
    float4 b = ((const float4*)rboxes)[memRank[g]];
    return make_float4(b.x + off, b.y + off, b.z + off, b.w + off);
}
__device__ inline float nms_area(u32 g, const float* __restrict__ areaL, float4 b) {
    if (g < (u32)MCAP) return areaL[g];
    return (b.z - b.x) * (b.w - b.y);
}

__global__ void __launch_bounds__(256) k_nms(const float* __restrict__ rboxes,
                                             const float* __restrict__ rvals,
                                             const int* __restrict__ rlabel,
                                             float* __restrict__ out) {
    int c = blockIdx.x + 1;                     // labels 1..80
    __shared__ float4 boxL[MCAP];
    __shared__ float areaL[MCAP];
    __shared__ unsigned short memRank[TOPK];
    __shared__ u32 cc[64];
    __shared__ u32 baseC[64];
    __shared__ u64 removedW[64];
    __shared__ u32 mTotSh;
    const int t = threadIdx.x;
    const int w = t >> 6, lane = t & 63;
    const u64 laneLT = ((u64)1 << lane) - 1;
    const float off = (float)c * 4096.0f;

    for (int it = 0; it < 16; it++) {
        int chunk = it * 4 + w;
        int r = chunk * 64 + lane;
        u64 mask = __ballot(rlabel[r] == c);
        if (lane == 0) cc[chunk] = (u32)__popcll(mask);
    }
    __syncthreads();
    if (t < 64) {
        u32 v = cc[t];
        u32 inc = v;
        #pragma unroll
        for (int d = 1; d < 64; d <<= 1) {
            u32 o = __shfl_up(inc, d);
            if (lane >= d) inc += o;
        }
        baseC[t] = inc - v;
        if (t == 63) mTotSh = inc;
    }
    __syncthreads();
    const u32 m = mTotSh;
    for (int it = 0; it < 16; it++) {
        int chunk = it * 4 + w;
        int r = chunk * 64 + lane;
        bool match = (rlabel[r] == c);
        u64 mask = __ballot(match);
        if (match) {
            u32 g = baseC[chunk] + (u32)__popcll(mask & laneLT);
            memRank[g] = (unsigned short)r;
            if (g < (u32)MCAP) {
                float4 b = ((const float4*)rboxes)[r];
                float bx1 = b.x + off, by1 = b.y + off;
                float bx2 = b.z + off, by2 = b.w + off;
                boxL[g] = make_float4(bx1, by1, bx2, by2);
                areaL[g] = (bx2 - bx1) * (by2 - by1);
            }
        }
    }
    __syncthreads();

    if (t < 64) {
        u32 nTiles = (m + 63) >> 6;
        for (u32 T = 0; T < nTiles; T++) {
            u32 tsize = m - T * 64; if (tsize > 64) tsize = 64;
            u32 g = T * 64 + (u32)lane;
            bool active = (u32)lane < tsize;
            float4 myB = make_float4(0, 0, 0, 0);
            float myA = 0.0f;
            if (active) {
                myB = nms_box(g, boxL, rboxes, memRank, off);
                myA = nms_area(g, areaL, myB);
            }
            bool supPrev = false;
            for (u32 P = 0; P < T; P++) {
                u64 remP = removedW[P];
                for (u32 s2 = 0; s2 < 64; s2++) {
                    if ((remP >> s2) & 1) continue;
                    u32 p = P * 64 + s2;
                    float4 bs = nms_box(p, boxL, rboxes, memRank, off);
                    float as = nms_area(p, areaL, bs);
                    if (active) {
                        float iw = fmaxf(fminf(myB.z, bs.z) - fmaxf(myB.x, bs.x), 0.0f);
                        float ih = fmaxf(fminf(myB.w, bs.w) - fmaxf(myB.y, bs.y), 0.0f);
                        float inter = iw * ih;
                        float iou = inter / (as + myA - inter + 1e-9f);
                        supPrev |= (iou > 0.5f);
                    }
                }
            }
            u64 colmask = 0;
            for (u32 s2 = 0; s2 + 1 < tsize; s2++) {
                u32 p = T * 64 + s2;
                float4 bs = nms_box(p, boxL, rboxes, memRank, off);
                float as = nms_area(p, areaL, bs);
                bool sup = false;
                if (active && (u32)lane > s2) {
                    float iw = fmaxf(fminf(myB.z, bs.z) - fmaxf(myB.x, bs.x), 0.0f);
                    float ih = fmaxf(fminf(myB.w, bs.w) - fmaxf(myB.y, bs.y), 0.0f);
                    float inter = iw * ih;
                    float iou = inter / (as + myA - inter + 1e-9f);
                    sup = (iou > 0.5f);
                }
                u64 ball = __ballot(sup);
                if ((u32)lane == s2) colmask = ball;
            }
            u64 rem = __ballot(supPrev && active);
            for (u32 s2 = 0; s2 < tsize; s2++) {
                u64 col = __shfl(colmask, (int)s2);
                if (!((rem >> s2) & 1)) rem |= col;
            }
            if (lane == 0) removedW[T] = rem;
        }
    }
    __syncthreads();

    for (u32 q = t; q < m; q += 256) {
        bool keep = !((removedW[q >> 6] >> (q & 63)) & 1);
        int r = memRank[q];
        out[TOPK * 6 + r] = keep ? 1.0f : 0.0f;
        float* d = out + (size_t)r * 5;
        if (keep) {
            float4 b = ((const float4*)rboxes)[r];
            d[0] = b.x; d[1] = b.y; d[2] = b.z; d[3] = b.w;
            d[4] = rvals[r];
        } else {
            d[0] = 0; d[1] = 0; d[2] = 0; d[3] = 0; d[4] = 0;
        }
    }
}

extern "C" void kernel_launch(void* const* d_in, const int* in_sizes, int n_in,
                              void* d_out, int out_size, void* d_ws, size_t ws_size,
                              hipStream_t stream) {
    const float* x = (const float*)d_in[0];
    const float* boxes = (const float*)d_in[1];
    float* out = (float*)d_out;

    u32* W = (u32*)d_ws;
    u32* cnt = W;                                          // 16
    u32* hist1p = W + 16;                                  // 64*576 = 36864
    u32* binCur = W + 16 + 36864;                          // 576
    u32* sufG = binCur + 576;                              // 584 (577 used)
    u32* candKey = sufG + 584;                             // MAXCAND
    u32* candIdx = candKey + MAXCAND;                      // MAXCAND
    u64* sel = (u64*)(candIdx + MAXCAND);                  // 4096 u64 (8B aligned)
    u32* eqI = (u32*)(sel + TOPK);                         // 8192
    float* rboxes = (float*)(eqI + EQCAP);                 // 16384
    float* rvals = rboxes + 4 * TOPK;                      // 4096
    int* rlabel = (int*)(rvals + TOPK);                    // 4096

    // zero: cnt + hist1p + binCur (contiguous, ~150 KB)
    hipMemsetAsync(W, 0, (16 + 36864 + 576) * sizeof(u32), stream);
    k_cand<<<CAND_GRID, CAND_THREADS, 0, stream>>>(x, candKey, candIdx, cnt, hist1p);
    k_mid<<<1, 1024, 0, stream>>>(candKey, hist1p, cnt, sufG);
    k_collect<<<COLL_GRID, 256, 0, stream>>>(candKey, candIdx, cnt, sufG, binCur, sel, eqI);
    k_binrank<<<H1_BINS + 1, 256, 0, stream>>>(sel, eqI, cnt, sufG, boxes,
                                               rboxes, rvals, rlabel, out);
    k_nms<<<80, 256, 0, stream>>>(rboxes, rvals, rlabel, out);
}

// Round 14
// 135.763 us; speedup vs baseline: 1.2536x; 1.2536x over previous
//
#include <hip/hip_runtime.h>

#pragma clang fp contract(off)

typedef unsigned int u32;
typedef unsigned long long u64;
typedef long long i64;

#define N_ROWS 32768
#define NCLS 81
#define TOPK 4096
#define MAXCAND 327680
#define SELCAP 12288                      // TOPK + bin-B slack (8192)
#define IMGW_M1 1332.0f
#define IMGH_M1 799.0f

// k_cand geometry: 8 threads/row, 32 rows/block, 1024 blocks
#define CAND_THREADS 256
#define RPB 32
#define CAND_GRID (N_ROWS / RPB)          // 1024
#define CPT 11
#define BLK_CAND_CAP 640                  // 32 rows * <=19 cand/row = 608 max
#define ROW_F4 ((RPB * NCLS) / 4)         // 648 float4 per block slice (exactly)

// level-1 bins: f32 bits of p in (0.05, 1.0] -> hi16 in [0x3D4C, 0x3F80]
#define H1_BASE 0x3D4Cu
#define H1_BINS 576
#define H1_SLICES 64

#define COLL_GRID 512
#define SEG_LDS 4096                      // binrank LDS segment cap (u64)

// k_nms LDS staging cap
#define MCAP 2048

// fast f64 exp for d <= 0 (clamped at -45). Cody-Waite + Taylor-13.
// Relative error ~3e-16 — decisions have >= f32-ulp (6e-8) margins.
__device__ inline double fast_exp_neg(double d) {
    if (d < -45.0) return 0.0;
    const double L2E    = 1.4426950408889634074;
    const double LN2_HI = 6.93147180369123816490e-01;
    const double LN2_LO = 1.90821492927058770002e-10;
    double n = __builtin_rint(d * L2E);
    double r = __builtin_fma(-n, LN2_HI, d);
    r = __builtin_fma(-n, LN2_LO, r);
    double p = 1.0 / 6227020800.0;
    p = __builtin_fma(p, r, 1.0 / 479001600.0);
    p = __builtin_fma(p, r, 1.0 / 39916800.0);
    p = __builtin_fma(p, r, 1.0 / 3628800.0);
    p = __builtin_fma(p, r, 1.0 / 362880.0);
    p = __builtin_fma(p, r, 1.0 / 40320.0);
    p = __builtin_fma(p, r, 1.0 / 5040.0);
    p = __builtin_fma(p, r, 1.0 / 720.0);
    p = __builtin_fma(p, r, 1.0 / 120.0);
    p = __builtin_fma(p, r, 1.0 / 24.0);
    p = __builtin_fma(p, r, 1.0 / 6.0);
    p = __builtin_fma(p, r, 0.5);
    p = __builtin_fma(p, r, 1.0);
    p = __builtin_fma(p, r, 1.0);
    i64 ni = (i64)n;
    double sc = __longlong_as_double((i64)(1023 + ni) << 52);
    return p * sc;
}

// softmax + threshold + DENSE compaction + FUSED level-1 histogram.
// Decision arithmetic identical to passing R13 -> bit-identical.
__global__ void __launch_bounds__(256) k_cand(const float* __restrict__ x,
                                              u32* __restrict__ candKey,
                                              u32* __restrict__ candIdx,
                                              u32* __restrict__ cnt,
                                              u32* __restrict__ hist1p) {
    __shared__ float4 lx4[ROW_F4];
    __shared__ u32 lK[BLK_CAND_CAP];
    __shared__ u32 lI[BLK_CAND_CAP];
    __shared__ u32 lh[H1_BINS];
    __shared__ u32 lcnt;
    __shared__ u32 gbaseSh;
    float* lx = (float*)lx4;
    const int t = threadIdx.x;
    if (t == 0) lcnt = 0;
    for (int i = t; i < H1_BINS; i += CAND_THREADS) lh[i] = 0;

    const float4* xv = (const float4*)x + (size_t)blockIdx.x * ROW_F4;
    for (int i = t; i < ROW_F4; i += CAND_THREADS) lx4[i] = xv[i];
    __syncthreads();

    const int rl = t >> 3;
    const int q = t & 7;
    const int c0 = q * 10;
    const int cEff = (q == 7) ? 11 : 10;
    const int row = blockIdx.x * RPB + rl;
    const float* xr = lx + rl * NCLS;

    float v[CPT];
    #pragma unroll
    for (int i = 0; i < CPT; i++) v[i] = (i < cEff) ? xr[c0 + i] : -1.0e30f;

    float m = v[0];
    #pragma unroll
    for (int i = 1; i < CPT; i++) m = fmaxf(m, v[i]);
    m = fmaxf(m, __shfl_xor(m, 1));
    m = fmaxf(m, __shfl_xor(m, 2));
    m = fmaxf(m, __shfl_xor(m, 4));

    double e[CPT];
    #pragma unroll
    for (int i = 0; i < CPT; i++) {
        if (i < cEff) {
            float d = v[i] - m;                   // f32 subtract, as reference
            e[i] = fast_exp_neg((double)d);
        } else e[i] = 0.0;
    }
    double s = 0.0;
    #pragma unroll
    for (int i = 0; i < CPT; i++) if (i < cEff) s += e[i];
    s += __shfl_xor(s, 1);
    s += __shfl_xor(s, 2);
    s += __shfl_xor(s, 4);

    const double THRMID = (double)0.05f + 0x1.0p-29;
    double ethr = THRMID * s;
    #pragma unroll
    for (int i = 0; i < CPT; i++) {
        int c = c0 + i;
        if (i < cEff && c != 0 && e[i] > ethr) {
            float pf = (float)(e[i] / s);         // exact f64 division, rare
            u32 slot = atomicAdd(&lcnt, 1u);
            lK[slot] = __float_as_uint(pf);
            lI[slot] = (u32)(row * NCLS + c);
        }
    }
    __syncthreads();
    u32 tot = lcnt;
    if (t == 0) gbaseSh = tot ? atomicAdd(&cnt[0], tot) : 0u;
    for (u32 i = t; i < tot; i += CAND_THREADS) {
        u32 b = (lK[i] >> 16) - H1_BASE;
        if (b < (u32)H1_BINS) atomicAdd(&lh[b], 1u);
    }
    __syncthreads();
    u32 gbase = gbaseSh;
    for (u32 i = t; i < tot; i += CAND_THREADS) {
        u32 g = gbase + i;
        if (g < MAXCAND) {
            candKey[g] = lK[i];
            candIdx[g] = lI[i];
        }
    }
    u32 ob = (blockIdx.x & (H1_SLICES - 1)) * H1_BINS;
    for (int i = t; i < H1_BINS; i += CAND_THREADS) {
        u32 h = lh[i];
        if (h) atomicAdd(&hist1p[ob + i], h);
    }
}

// lite cutoff finder: sum partials + suffix scan + find cutoff BIN only.
// No level-2/3 candidate scans, no exact cut key — bin + within-bin rank
// (in k_binrank) selects the identical top-TOPK set and order.
__global__ void __launch_bounds__(1024) k_midlite(const u32* __restrict__ hist1p,
                                                  u32* __restrict__ cnt,
                                                  u32* __restrict__ sufG) {
    __shared__ u32 cs[1024];
    int t = threadIdx.x;
    u32 s1 = 0;
    if (t < H1_BINS) {
        for (int j = 0; j < H1_SLICES; j++) s1 += hist1p[j * H1_BINS + t];  // coalesced
    }
    cs[t] = (t < H1_BINS) ? s1 : 0u;
    __syncthreads();
    for (int d = 1; d < 1024; d <<= 1) {          // inclusive suffix sum
        u32 v = (t + d < 1024) ? cs[t + d] : 0u;
        __syncthreads();
        cs[t] += v;
        __syncthreads();
    }
    if (t < 577) sufG[t] = cs[t];                 // cs[576] == 0 naturally
    u32 S_t = cs[t];
    u32 S_next = (t < 1023) ? cs[t + 1] : 0u;
    if (S_next < TOPK && S_t >= TOPK) cnt[3] = (u32)t;  // cutoff bin B
    // if total < TOPK no thread matches; cnt[3] stays 0 (memset) -> scatter all
}

// scatter candidates with bin >= B directly into per-bin segments of sel[]
__global__ void __launch_bounds__(256) k_collect(const u32* __restrict__ candKey,
                                                 const u32* __restrict__ candIdx,
                                                 u32* __restrict__ cnt,
                                                 const u32* __restrict__ sufG,
                                                 u32* __restrict__ binCur,
                                                 u64* __restrict__ sel) {
    u32 n = cnt[0] < (u32)MAXCAND ? cnt[0] : (u32)MAXCAND;
    u32 B = cnt[3];
    u32 stride = COLL_GRID * 256;
    for (u32 i = blockIdx.x * 256 + threadIdx.x; i < n; i += stride) {
        u32 k = candKey[i];
        u32 b = (k >> 16) - H1_BASE;
        if (b < (u32)H1_BINS && b >= B) {
            u32 pos = sufG[b + 1] + atomicAdd(&binCur[b], 1u);
            if (pos < (u32)SELCAP)
                sel[pos] = ((u64)k << 32) | (u64)(0xFFFFFFFFu - candIdx[i]);
        }
    }
}

// distributed ranking: one block per level-1 bin; within-bin quadratic rank
// over composite (value-desc, idx-asc). Global rank = sufG[b+1] + local rank;
// emit only ranks < TOPK (filters bin B's overflow — exact cutoff semantics).
// Block 576 zeroes the degenerate-underfill tail.
__global__ void __launch_bounds__(256) k_binrank(const u64* __restrict__ sel,
                                                 const u32* __restrict__ cnt,
                                                 const u32* __restrict__ sufG,
                                                 const float* __restrict__ boxes,
                                                 float* __restrict__ rboxes,
                                                 float* __restrict__ rvals,
                                                 int* __restrict__ rlabel,
                                                 float* __restrict__ out) {
    const int t = threadIdx.x;
    const u32 B = cnt[3];

    if (blockIdx.x == H1_BINS) {                  // tail block (degenerate only)
        u32 covered = sufG[B];
        if (covered > (u32)TOPK) covered = TOPK;
        for (u32 r = covered + t; r < TOPK; r += 256) {
            rboxes[r * 4 + 0] = 0; rboxes[r * 4 + 1] = 0;
            rboxes[r * 4 + 2] = 0; rboxes[r * 4 + 3] = 0;
            rvals[r] = 0.0f; rlabel[r] = 0;
            out[TOPK * 5 + r] = 0.0f;
            out[TOPK * 6 + r] = 0.0f;
            float* d = out + (size_t)r * 5;
            d[0] = 0; d[1] = 0; d[2] = 0; d[3] = 0; d[4] = 0;
        }
        return;
    }

    __shared__ u64 seg[SEG_LDS];                  // 32 KB
    const u32 b = blockIdx.x;
    if (b < B) return;
    u32 start = sufG[b + 1];
    u32 end = sufG[b];
    if (end > (u32)SELCAP) end = SELCAP;
    if (start >= end) return;
    u32 len = end - start;
    // bins > B never overflow TOPK; only bin B can have start >= TOPK members all filtered
    if (start >= (u32)TOPK) return;
    u32 ldsLen = len < (u32)SEG_LDS ? len : (u32)SEG_LDS;
    for (u32 i = t; i < ldsLen; i += 256) seg[i] = sel[start + i];
    __syncthreads();
    for (u32 i = t; i < len; i += 256) {
        u64 c = (i < ldsLen) ? seg[i] : sel[start + i];
        u32 r0 = 0;
        for (u32 j = 0; j < ldsLen; j++) r0 += (seg[j] > c) ? 1u : 0u;
        for (u32 j = ldsLen; j < len; j++) r0 += (sel[start + j] > c) ? 1u : 0u;
        u32 r = start + r0;
        if (r >= (u32)TOPK) continue;             // bin-B overflow: below cutoff
        u32 idx = 0xFFFFFFFFu - (u32)(c & 0xFFFFFFFFull);
        float val = __uint_as_float((u32)(c >> 32));
        u32 bi = idx / NCLS;
        u32 lab = idx % NCLS;
        const float* bp = boxes + (size_t)bi * 4;
        float x1 = fminf(fmaxf(bp[0], 0.0f), IMGW_M1);
        float y1 = fminf(fmaxf(bp[1], 0.0f), IMGH_M1);
        float x2 = fminf(fmaxf(bp[2], 0.0f), IMGW_M1);
        float y2 = fminf(fmaxf(bp[3], 0.0f), IMGH_M1);
        rboxes[r * 4 + 0] = x1; rboxes[r * 4 + 1] = y1;
        rboxes[r * 4 + 2] = x2; rboxes[r * 4 + 3] = y2;
        rvals[r] = val;
        rlabel[r] = (int)lab;
        out[TOPK * 5 + r] = (float)lab;           // labels (unmasked in reference)
    }
}

// ---- tiled bitmask greedy NMS (R11-R13, verified) ----
__device__ inline float4 nms_box(u32 g, const float4* __restrict__ boxL,
                                 const float* __restrict__ rboxes,
                                 const unsigned short* __restrict__ memRank, float off) {
    if (g < (u32)MCAP) return boxL[g];
    float4 b = ((const float4*)rboxes)[memRank[g]];
    return make_float4(b.x + off, b.y + off, b.z + off, b.w + off);
}
__device__ inline float nms_area(u32 g, const float* __restrict__ areaL, float4 b) {
    if (g < (u32)MCAP) return areaL[g];
    return (b.z - b.x) * (b.w - b.y);
}

__global__ void __launch_bounds__(256) k_nms(const float* __restrict__ rboxes,
                                             const float* __restrict__ rvals,
                                             const int* __restrict__ rlabel,
                                             float* __restrict__ out) {
    int c = blockIdx.x + 1;                     // labels 1..80
    __shared__ float4 boxL[MCAP];
    __shared__ float areaL[MCAP];
    __shared__ unsigned short memRank[TOPK];
    __shared__ u32 cc[64];
    __shared__ u32 baseC[64];
    __shared__ u64 removedW[64];
    __shared__ u32 mTotSh;
    const int t = threadIdx.x;
    const int w = t >> 6, lane = t & 63;
    const u64 laneLT = ((u64)1 << lane) - 1;
    const float off = (float)c * 4096.0f;

    for (int it = 0; it < 16; it++) {
        int chunk = it * 4 + w;
        int r = chunk * 64 + lane;
        u64 mask = __ballot(rlabel[r] == c);
        if (lane == 0) cc[chunk] = (u32)__popcll(mask);
    }
    __syncthreads();
    if (t < 64) {
        u32 v = cc[t];
        u32 inc = v;
        #pragma unroll
        for (int d = 1; d < 64; d <<= 1) {
            u32 o = __shfl_up(inc, d);
            if (lane >= d) inc += o;
        }
        baseC[t] = inc - v;
        if (t == 63) mTotSh = inc;
    }
    __syncthreads();
    const u32 m = mTotSh;
    for (int it = 0; it < 16; it++) {
        int chunk = it * 4 + w;
        int r = chunk * 64 + lane;
        bool match = (rlabel[r] == c);
        u64 mask = __ballot(match);
        if (match) {
            u32 g = baseC[chunk] + (u32)__popcll(mask & laneLT);
            memRank[g] = (unsigned short)r;
            if (g < (u32)MCAP) {
                float4 b = ((const float4*)rboxes)[r];
                float bx1 = b.x + off, by1 = b.y + off;
                float bx2 = b.z + off, by2 = b.w + off;
                boxL[g] = make_float4(bx1, by1, bx2, by2);
                areaL[g] = (bx2 - bx1) * (by2 - by1);
            }
        }
    }
    __syncthreads();

    if (t < 64) {
        u32 nTiles = (m + 63) >> 6;
        for (u32 T = 0; T < nTiles; T++) {
            u32 tsize = m - T * 64; if (tsize > 64) tsize = 64;
            u32 g = T * 64 + (u32)lane;
            bool active = (u32)lane < tsize;
            float4 myB = make_float4(0, 0, 0, 0);
            float myA = 0.0f;
            if (active) {
                myB = nms_box(g, boxL, rboxes, memRank, off);
                myA = nms_area(g, areaL, myB);
            }
            bool supPrev = false;
            for (u32 P = 0; P < T; P++) {
                u64 remP = removedW[P];
                for (u32 s2 = 0; s2 < 64; s2++) {
                    if ((remP >> s2) & 1) continue;
                    u32 p = P * 64 + s2;
                    float4 bs = nms_box(p, boxL, rboxes, memRank, off);
                    float as = nms_area(p, areaL, bs);
                    if (active) {
                        float iw = fmaxf(fminf(myB.z, bs.z) - fmaxf(myB.x, bs.x), 0.0f);
                        float ih = fmaxf(fminf(myB.w, bs.w) - fmaxf(myB.y, bs.y), 0.0f);
                        float inter = iw * ih;
                        float iou = inter / (as + myA - inter + 1e-9f);
                        supPrev |= (iou > 0.5f);
                    }
                }
            }
            u64 colmask = 0;
            for (u32 s2 = 0; s2 + 1 < tsize; s2++) {
                u32 p = T * 64 + s2;
                float4 bs = nms_box(p, boxL, rboxes, memRank, off);
                float as = nms_area(p, areaL, bs);
                bool sup = false;
                if (active && (u32)lane > s2) {
                    float iw = fmaxf(fminf(myB.z, bs.z) - fmaxf(myB.x, bs.x), 0.0f);
                    float ih = fmaxf(fminf(myB.w, bs.w) - fmaxf(myB.y, bs.y), 0.0f);
                    float inter = iw * ih;
                    float iou = inter / (as + myA - inter + 1e-9f);
                    sup = (iou > 0.5f);
                }
                u64 ball = __ballot(sup);
                if ((u32)lane == s2) colmask = ball;
            }
            u64 rem = __ballot(supPrev && active);
            for (u32 s2 = 0; s2 < tsize; s2++) {
                u64 col = __shfl(colmask, (int)s2);
                if (!((rem >> s2) & 1)) rem |= col;
            }
            if (lane == 0) removedW[T] = rem;
        }
    }
    __syncthreads();

    for (u32 q = t; q < m; q += 256) {
        bool keep = !((removedW[q >> 6] >> (q & 63)) & 1);
        int r = memRank[q];
        out[TOPK * 6 + r] = keep ? 1.0f : 0.0f;
        float* d = out + (size_t)r * 5;
        if (keep) {
            float4 b = ((const float4*)rboxes)[r];
            d[0] = b.x; d[1] = b.y; d[2] = b.z; d[3] = b.w;
            d[4] = rvals[r];
        } else {
            d[0] = 0; d[1] = 0; d[2] = 0; d[3] = 0; d[4] = 0;
        }
    }
}

extern "C" void kernel_launch(void* const* d_in, const int* in_sizes, int n_in,
                              void* d_out, int out_size, void* d_ws, size_t ws_size,
                              hipStream_t stream) {
    const float* x = (const float*)d_in[0];
    const float* boxes = (const float*)d_in[1];
    float* out = (float*)d_out;

    u32* W = (u32*)d_ws;
    u32* cnt = W;                                          // 16
    u32* hist1p = W + 16;                                  // 64*576 = 36864
    u32* binCur = W + 16 + 36864;                          // 576
    u32* sufG = binCur + 576;                              // 584 (577 used)
    u32* candKey = sufG + 584;                             // MAXCAND
    u32* candIdx = candKey + MAXCAND;                      // MAXCAND
    u64* sel = (u64*)(candIdx + MAXCAND);                  // SELCAP u64 (8B aligned)
    float* rboxes = (float*)(sel + SELCAP);                // 16384
    float* rvals = rboxes + 4 * TOPK;                      // 4096
    int* rlabel = (int*)(rvals + TOPK);                    // 4096

    // zero: cnt + hist1p + binCur (contiguous, ~150 KB)
    hipMemsetAsync(W, 0, (16 + 36864 + 576) * sizeof(u32), stream);
    k_cand<<<CAND_GRID, CAND_THREADS, 0, stream>>>(x, candKey, candIdx, cnt, hist1p);
    k_midlite<<<1, 1024, 0, stream>>>(hist1p, cnt, sufG);
    k_collect<<<COLL_GRID, 256, 0, stream>>>(candKey, candIdx, cnt, sufG, binCur, sel);
    k_binrank<<<H1_BINS + 1, 256, 0, stream>>>(sel, cnt, sufG, boxes,
                                               rboxes, rvals, rlabel, out);
    k_nms<<<80, 256, 0, stream>>>(rboxes, rvals, rlabel, out);
}

// Round 15
// 115.941 us; speedup vs baseline: 1.4679x; 1.1710x over previous
//
#include <hip/hip_runtime.h>

#pragma clang fp contract(off)

typedef unsigned int u32;
typedef unsigned long long u64;
typedef long long i64;

#define N_ROWS 32768
#define NCLS 81
#define TOPK 4096
#define MAXCAND 327680
#define SELCAP 12288                      // TOPK + bin-B slack (8192)
#define IMGW_M1 1332.0f
#define IMGH_M1 799.0f

// k_cand geometry: 8 threads/row, 32 rows/block, 1024 blocks
#define CAND_THREADS 256
#define RPB 32
#define CAND_GRID (N_ROWS / RPB)          // 1024
#define CPT 11
#define BLK_CAND_CAP 640                  // 32 rows * <=19 cand/row = 608 max
#define ROW_F4 ((RPB * NCLS) / 4)         // 648 float4 per block slice (exactly)

// level-1 bins: f32 bits of p in (0.05, 1.0] -> hi16 in [0x3D4C, 0x3F80]
#define H1_BASE 0x3D4Cu
#define H1_BINS 576
#define H1_SLICES 64

#define COLL_GRID 512
#define SEG_LDS 4096                      // binrank LDS segment cap (u64)

// k_nms: LDS box stage cap / matrix-path cap
#define MCAP 1024
#define MMAX 512
#define NW32 16                           // MMAX/32 words per column

// fast f64 exp for d <= 0 (clamped at -45). Cody-Waite + Taylor-13.
// Relative error ~3e-16 — decisions have >= f32-ulp (6e-8) margins.
__device__ inline double fast_exp_neg(double d) {
    if (d < -45.0) return 0.0;
    const double L2E    = 1.4426950408889634074;
    const double LN2_HI = 6.93147180369123816490e-01;
    const double LN2_LO = 1.90821492927058770002e-10;
    double n = __builtin_rint(d * L2E);
    double r = __builtin_fma(-n, LN2_HI, d);
    r = __builtin_fma(-n, LN2_LO, r);
    double p = 1.0 / 6227020800.0;
    p = __builtin_fma(p, r, 1.0 / 479001600.0);
    p = __builtin_fma(p, r, 1.0 / 39916800.0);
    p = __builtin_fma(p, r, 1.0 / 3628800.0);
    p = __builtin_fma(p, r, 1.0 / 362880.0);
    p = __builtin_fma(p, r, 1.0 / 40320.0);
    p = __builtin_fma(p, r, 1.0 / 5040.0);
    p = __builtin_fma(p, r, 1.0 / 720.0);
    p = __builtin_fma(p, r, 1.0 / 120.0);
    p = __builtin_fma(p, r, 1.0 / 24.0);
    p = __builtin_fma(p, r, 1.0 / 6.0);
    p = __builtin_fma(p, r, 0.5);
    p = __builtin_fma(p, r, 1.0);
    p = __builtin_fma(p, r, 1.0);
    i64 ni = (i64)n;
    double sc = __longlong_as_double((i64)(1023 + ni) << 52);
    return p * sc;
}

// softmax + threshold + DENSE compaction + FUSED level-1 histogram.
// Decision arithmetic identical to passing R14 -> bit-identical.
__global__ void __launch_bounds__(256) k_cand(const float* __restrict__ x,
                                              u32* __restrict__ candKey,
                                              u32* __restrict__ candIdx,
                                              u32* __restrict__ cnt,
                                              u32* __restrict__ hist1p) {
    __shared__ float4 lx4[ROW_F4];
    __shared__ u32 lK[BLK_CAND_CAP];
    __shared__ u32 lI[BLK_CAND_CAP];
    __shared__ u32 lh[H1_BINS];
    __shared__ u32 lcnt;
    __shared__ u32 gbaseSh;
    float* lx = (float*)lx4;
    const int t = threadIdx.x;
    if (t == 0) lcnt = 0;
    for (int i = t; i < H1_BINS; i += CAND_THREADS) lh[i] = 0;

    const float4* xv = (const float4*)x + (size_t)blockIdx.x * ROW_F4;
    for (int i = t; i < ROW_F4; i += CAND_THREADS) lx4[i] = xv[i];
    __syncthreads();

    const int rl = t >> 3;
    const int q = t & 7;
    const int c0 = q * 10;
    const int cEff = (q == 7) ? 11 : 10;
    const int row = blockIdx.x * RPB + rl;
    const float* xr = lx + rl * NCLS;

    float v[CPT];
    #pragma unroll
    for (int i = 0; i < CPT; i++) v[i] = (i < cEff) ? xr[c0 + i] : -1.0e30f;

    float m = v[0];
    #pragma unroll
    for (int i = 1; i < CPT; i++) m = fmaxf(m, v[i]);
    m = fmaxf(m, __shfl_xor(m, 1));
    m = fmaxf(m, __shfl_xor(m, 2));
    m = fmaxf(m, __shfl_xor(m, 4));

    double e[CPT];
    #pragma unroll
    for (int i = 0; i < CPT; i++) {
        if (i < cEff) {
            float d = v[i] - m;                   // f32 subtract, as reference
            e[i] = fast_exp_neg((double)d);
        } else e[i] = 0.0;
    }
    double s = 0.0;
    #pragma unroll
    for (int i = 0; i < CPT; i++) if (i < cEff) s += e[i];
    s += __shfl_xor(s, 1);
    s += __shfl_xor(s, 2);
    s += __shfl_xor(s, 4);

    const double THRMID = (double)0.05f + 0x1.0p-29;
    double ethr = THRMID * s;
    #pragma unroll
    for (int i = 0; i < CPT; i++) {
        int c = c0 + i;
        if (i < cEff && c != 0 && e[i] > ethr) {
            float pf = (float)(e[i] / s);         // exact f64 division, rare
            u32 slot = atomicAdd(&lcnt, 1u);
            lK[slot] = __float_as_uint(pf);
            lI[slot] = (u32)(row * NCLS + c);
        }
    }
    __syncthreads();
    u32 tot = lcnt;
    if (t == 0) gbaseSh = tot ? atomicAdd(&cnt[0], tot) : 0u;
    for (u32 i = t; i < tot; i += CAND_THREADS) {
        u32 b = (lK[i] >> 16) - H1_BASE;
        if (b < (u32)H1_BINS) atomicAdd(&lh[b], 1u);
    }
    __syncthreads();
    u32 gbase = gbaseSh;
    for (u32 i = t; i < tot; i += CAND_THREADS) {
        u32 g = gbase + i;
        if (g < MAXCAND) {
            candKey[g] = lK[i];
            candIdx[g] = lI[i];
        }
    }
    u32 ob = (blockIdx.x & (H1_SLICES - 1)) * H1_BINS;
    for (int i = t; i < H1_BINS; i += CAND_THREADS) {
        u32 h = lh[i];
        if (h) atomicAdd(&hist1p[ob + i], h);
    }
}

// lite cutoff finder: sum partials + suffix scan + find cutoff BIN only.
__global__ void __launch_bounds__(1024) k_midlite(const u32* __restrict__ hist1p,
                                                  u32* __restrict__ cnt,
                                                  u32* __restrict__ sufG) {
    __shared__ u32 cs[1024];
    int t = threadIdx.x;
    u32 s1 = 0;
    if (t < H1_BINS) {
        for (int j = 0; j < H1_SLICES; j++) s1 += hist1p[j * H1_BINS + t];  // coalesced
    }
    cs[t] = (t < H1_BINS) ? s1 : 0u;
    __syncthreads();
    for (int d = 1; d < 1024; d <<= 1) {          // inclusive suffix sum
        u32 v = (t + d < 1024) ? cs[t + d] : 0u;
        __syncthreads();
        cs[t] += v;
        __syncthreads();
    }
    if (t < 577) sufG[t] = cs[t];                 // cs[576] == 0 naturally
    u32 S_t = cs[t];
    u32 S_next = (t < 1023) ? cs[t + 1] : 0u;
    if (S_next < TOPK && S_t >= TOPK) cnt[3] = (u32)t;  // cutoff bin B
}

// scatter candidates with bin >= B directly into per-bin segments of sel[]
__global__ void __launch_bounds__(256) k_collect(const u32* __restrict__ candKey,
                                                 const u32* __restrict__ candIdx,
                                                 u32* __restrict__ cnt,
                                                 const u32* __restrict__ sufG,
                                                 u32* __restrict__ binCur,
                                                 u64* __restrict__ sel) {
    u32 n = cnt[0] < (u32)MAXCAND ? cnt[0] : (u32)MAXCAND;
    u32 B = cnt[3];
    u32 stride = COLL_GRID * 256;
    for (u32 i = blockIdx.x * 256 + threadIdx.x; i < n; i += stride) {
        u32 k = candKey[i];
        u32 b = (k >> 16) - H1_BASE;
        if (b < (u32)H1_BINS && b >= B) {
            u32 pos = sufG[b + 1] + atomicAdd(&binCur[b], 1u);
            if (pos < (u32)SELCAP)
                sel[pos] = ((u64)k << 32) | (u64)(0xFFFFFFFFu - candIdx[i]);
        }
    }
}

// distributed ranking: one block per level-1 bin; within-bin quadratic rank
// over composite (value-desc, idx-asc). Emit only ranks < TOPK.
__global__ void __launch_bounds__(256) k_binrank(const u64* __restrict__ sel,
                                                 const u32* __restrict__ cnt,
                                                 const u32* __restrict__ sufG,
                                                 const float* __restrict__ boxes,
                                                 float* __restrict__ rboxes,
                                                 float* __restrict__ rvals,
                                                 int* __restrict__ rlabel,
                                                 float* __restrict__ out) {
    const int t = threadIdx.x;
    const u32 B = cnt[3];

    if (blockIdx.x == H1_BINS) {                  // tail block (degenerate only)
        u32 covered = sufG[B];
        if (covered > (u32)TOPK) covered = TOPK;
        for (u32 r = covered + t; r < TOPK; r += 256) {
            rboxes[r * 4 + 0] = 0; rboxes[r * 4 + 1] = 0;
            rboxes[r * 4 + 2] = 0; rboxes[r * 4 + 3] = 0;
            rvals[r] = 0.0f; rlabel[r] = 0;
            out[TOPK * 5 + r] = 0.0f;
            out[TOPK * 6 + r] = 0.0f;
            float* d = out + (size_t)r * 5;
            d[0] = 0; d[1] = 0; d[2] = 0; d[3] = 0; d[4] = 0;
        }
        return;
    }

    __shared__ u64 seg[SEG_LDS];                  // 32 KB
    const u32 b = blockIdx.x;
    if (b < B) return;
    u32 start = sufG[b + 1];
    u32 end = sufG[b];
    if (end > (u32)SELCAP) end = SELCAP;
    if (start >= end) return;
    u32 len = end - start;
    if (start >= (u32)TOPK) return;
    u32 ldsLen = len < (u32)SEG_LDS ? len : (u32)SEG_LDS;
    for (u32 i = t; i < ldsLen; i += 256) seg[i] = sel[start + i];
    __syncthreads();
    for (u32 i = t; i < len; i += 256) {
        u64 c = (i < ldsLen) ? seg[i] : sel[start + i];
        u32 r0 = 0;
        for (u32 j = 0; j < ldsLen; j++) r0 += (seg[j] > c) ? 1u : 0u;
        for (u32 j = ldsLen; j < len; j++) r0 += (sel[start + j] > c) ? 1u : 0u;
        u32 r = start + r0;
        if (r >= (u32)TOPK) continue;             // bin-B overflow: below cutoff
        u32 idx = 0xFFFFFFFFu - (u32)(c & 0xFFFFFFFFull);
        float val = __uint_as_float((u32)(c >> 32));
        u32 bi = idx / NCLS;
        u32 lab = idx % NCLS;
        const float* bp = boxes + (size_t)bi * 4;
        float x1 = fminf(fmaxf(bp[0], 0.0f), IMGW_M1);
        float y1 = fminf(fmaxf(bp[1], 0.0f), IMGH_M1);
        float x2 = fminf(fmaxf(bp[2], 0.0f), IMGW_M1);
        float y2 = fminf(fmaxf(bp[3], 0.0f), IMGH_M1);
        rboxes[r * 4 + 0] = x1; rboxes[r * 4 + 1] = y1;
        rboxes[r * 4 + 2] = x2; rboxes[r * 4 + 3] = y2;
        rvals[r] = val;
        rlabel[r] = (int)lab;
        out[TOPK * 5 + r] = (float)lab;           // labels (unmasked in reference)
    }
}

// ---- parallel-matrix greedy NMS, one block (256 thr) per class ----
// Suppression column-masks built by ALL 256 threads in one parallel sweep
// (unique writer per 32-bit word, no atomics); greedy scan is a register
// shuffle chain. IoU op order identical to reference iou_gt.
__device__ inline float4 nms_box(u32 g, const float4* __restrict__ boxL,
                                 const float* __restrict__ rboxes,
                                 const unsigned short* __restrict__ memRank, float off) {
    if (g < (u32)MCAP) return boxL[g];
    float4 b = ((const float4*)rboxes)[memRank[g]];     // fallback: never in practice
    return make_float4(b.x + off, b.y + off, b.z + off, b.w + off);
}
__device__ inline float nms_area(u32 g, const float* __restrict__ areaL, float4 b) {
    if (g < (u32)MCAP) return areaL[g];
    return (b.z - b.x) * (b.w - b.y);
}

__global__ void __launch_bounds__(256) k_nms(const float* __restrict__ rboxes,
                                             const float* __restrict__ rvals,
                                             const int* __restrict__ rlabel,
                                             float* __restrict__ out) {
    int c = blockIdx.x + 1;                     // labels 1..80
    __shared__ int lLab[TOPK];                  // 16 KB
    __shared__ float4 boxL[MCAP];               // 16 KB (offset boxes)
    __shared__ float areaL[MCAP];               // 4 KB
    __shared__ unsigned short memRank[TOPK];    // 8 KB
    __shared__ u32 colW[MMAX * NW32];           // 32 KB column-mask words
    __shared__ u32 remOut[NW32];
    __shared__ unsigned char keepL[TOPK];       // fallback only
    __shared__ u32 cc[64];
    __shared__ u32 baseC[64];
    __shared__ u32 mTotSh;
    const int t = threadIdx.x;
    const int w = t >> 6, lane = t & 63;
    const u64 laneLT = ((u64)1 << lane) - 1;
    const float off = (float)c * 4096.0f;       // reference's f32 offset rounding

    // stage labels into LDS (coalesced int4) — ballot rounds then hit LDS
    {
        const int4* g4 = (const int4*)rlabel;
        int4* l4 = (int4*)lLab;
        for (int i = t; i < TOPK / 4; i += 256) l4[i] = g4[i];
    }
    __syncthreads();

    // phase A: per-64-chunk counts
    for (int it = 0; it < 16; it++) {
        int chunk = it * 4 + w;
        int r = chunk * 64 + lane;
        u64 mask = __ballot(lLab[r] == c);
        if (lane == 0) cc[chunk] = (u32)__popcll(mask);
    }
    __syncthreads();
    // phase B: exclusive scan of 64 chunk counts (wave 0)
    if (t < 64) {
        u32 v = cc[t];
        u32 inc = v;
        #pragma unroll
        for (int d = 1; d < 64; d <<= 1) {
            u32 o = __shfl_up(inc, d);
            if (lane >= d) inc += o;
        }
        baseC[t] = inc - v;
        if (t == 63) mTotSh = inc;
    }
    __syncthreads();
    const u32 m = mTotSh;
    // phase C: stable scatter + stage offset boxes/areas
    for (int it = 0; it < 16; it++) {
        int chunk = it * 4 + w;
        int r = chunk * 64 + lane;
        bool match = (lLab[r] == c);
        u64 mask = __ballot(match);
        if (match) {
            u32 g = baseC[chunk] + (u32)__popcll(mask & laneLT);
            memRank[g] = (unsigned short)r;
            if (g < (u32)MCAP) {
                float4 b = ((const float4*)rboxes)[r];
                float bx1 = b.x + off, by1 = b.y + off;
                float bx2 = b.z + off, by2 = b.w + off;
                boxL[g] = make_float4(bx1, by1, bx2, by2);
                areaL[g] = (bx2 - bx1) * (by2 - by1);   // reference: area on offset boxes
            }
        }
    }
    __syncthreads();

    const bool matrixPath = (m <= (u32)MMAX);
    if (matrixPath) {
        const u32 nW = (m + 31) >> 5;
        const u32 items = m * nW;
        // parallel column-mask build: item (s, wd) -> one 32-bit word
        for (u32 p = t; p < items; p += 256) {
            u32 s = p / nW;
            u32 wd = p - s * nW;
            float4 bs = nms_box(s, boxL, rboxes, memRank, off);
            float as = nms_area(s, areaL, bs);
            u32 word = 0;
            u32 j0 = wd << 5;
            u32 jend = j0 + 32; if (jend > m) jend = m;
            u32 js = (j0 > s + 1) ? j0 : (s + 1);
            for (u32 j = js; j < jend; j++) {
                float4 bj = nms_box(j, boxL, rboxes, memRank, off);
                float aj = nms_area(j, areaL, bj);
                float iw = fmaxf(fminf(bs.z, bj.z) - fmaxf(bs.x, bj.x), 0.0f);
                float ih = fmaxf(fminf(bs.w, bj.w) - fmaxf(bs.y, bj.y), 0.0f);
                float inter = iw * ih;
                float iou = inter / (as + aj - inter + 1e-9f);  // area_s + area_j: ref order
                if (iou > 0.5f) word |= (1u << (j - j0));
            }
            colW[s * NW32 + wd] = word;
        }
        __syncthreads();
        // greedy scan: wave 0, lane w holds rem-word w; shuffle-broadcast removed bit
        if (t < 64) {
            u32 remW = 0;
            bool own = ((u32)lane < ((m + 31) >> 5));
            for (u32 s2 = 0; s2 < m; s2++) {
                u32 rw = __shfl(remW, (int)(s2 >> 5));
                bool removed = (rw >> (s2 & 31)) & 1u;
                u32 cw = own ? colW[s2 * NW32 + lane] : 0u;
                if (!removed) remW |= cw;
            }
            if (own) remOut[lane] = remW;
        }
        __syncthreads();
    } else {
        // fallback (m > 512: statistically unreachable) — reference-style scan
        for (u32 q2 = t; q2 < m; q2 += 256) keepL[q2] = 1;
        __syncthreads();
        for (u32 i = 0; i < m; i++) {
            __syncthreads();
            if (!keepL[i]) continue;                 // uniform (shared value)
            float4 bi = nms_box(i, boxL, rboxes, memRank, off);
            float ai = nms_area(i, areaL, bi);
            for (u32 jj = i + 1 + t; jj < m; jj += 256) {
                if (!keepL[jj]) continue;
                float4 bj = nms_box(jj, boxL, rboxes, memRank, off);
                float aj = nms_area(jj, areaL, bj);
                float iw = fmaxf(fminf(bi.z, bj.z) - fmaxf(bi.x, bj.x), 0.0f);
                float ih = fmaxf(fminf(bi.w, bj.w) - fmaxf(bi.y, bj.y), 0.0f);
                float inter = iw * ih;
                float iou = inter / (ai + aj - inter + 1e-9f);
                if (iou > 0.5f) keepL[jj] = 0;
            }
        }
        __syncthreads();
    }

    // output
    for (u32 q2 = t; q2 < m; q2 += 256) {
        bool keep = matrixPath ? !((remOut[q2 >> 5] >> (q2 & 31)) & 1u)
                               : (keepL[q2] != 0);
        int r = memRank[q2];
        out[TOPK * 6 + r] = keep ? 1.0f : 0.0f;
        float* d = out + (size_t)r * 5;
        if (keep) {
            float4 b = ((const float4*)rboxes)[r];
            d[0] = b.x; d[1] = b.y; d[2] = b.z; d[3] = b.w;
            d[4] = rvals[r];
        } else {
            d[0] = 0; d[1] = 0; d[2] = 0; d[3] = 0; d[4] = 0;
        }
    }
}

extern "C" void kernel_launch(void* const* d_in, const int* in_sizes, int n_in,
                              void* d_out, int out_size, void* d_ws, size_t ws_size,
                              hipStream_t stream) {
    const float* x = (const float*)d_in[0];
    const float* boxes = (const float*)d_in[1];
    float* out = (float*)d_out;

    u32* W = (u32*)d_ws;
    u32* cnt = W;                                          // 16
    u32* hist1p = W + 16;                                  // 64*576 = 36864
    u32* binCur = W + 16 + 36864;                          // 576
    u32* sufG = binCur + 576;                              // 584 (577 used)
    u32* candKey = sufG + 584;                             // MAXCAND
    u32* candIdx = candKey + MAXCAND;                      // MAXCAND
    u64* sel = (u64*)(candIdx + MAXCAND);                  // SELCAP u64 (8B aligned)
    float* rboxes = (float*)(sel + SELCAP);                // 16384
    float* rvals = rboxes + 4 * TOPK;                      // 4096
    int* rlabel = (int*)(rvals + TOPK);                    // 4096

    // zero: cnt + hist1p + binCur (contiguous, ~150 KB)
    hipMemsetAsync(W, 0, (16 + 36864 + 576) * sizeof(u32), stream);
    k_cand<<<CAND_GRID, CAND_THREADS, 0, stream>>>(x, candKey, candIdx, cnt, hist1p);
    k_midlite<<<1, 1024, 0, stream>>>(hist1p, cnt, sufG);
    k_collect<<<COLL_GRID, 256, 0, stream>>>(candKey, candIdx, cnt, sufG, binCur, sel);
    k_binrank<<<H1_BINS + 1, 256, 0, stream>>>(sel, cnt, sufG, boxes,
                                               rboxes, rvals, rlabel, out);
    k_nms<<<80, 256, 0, stream>>>(rboxes, rvals, rlabel, out);
}